// Round 1
// 60.642 us; speedup vs baseline: 1.0213x; 1.0213x over previous
//
#include <hip/hip_runtime.h>

// Problem: N=2048, IN=32, SEG=16, OUT=64
// out[n,o] = sum_i [ (1-t_{n,i}) * yp[i, seg, o] + t_{n,i} * yp[i, seg+1, o] ]
// where t = (x - lo)/d is o-uniform (breakpoints broadcast along o), seg is the
// unique active segment (sorted breakpoints; continuity makes boundary ties
// value-identical; unclamped t reproduces both edge extensions).
//
// Restructure vs previous version (61.9 us total, kernel itself <39 us):
//  - 512 blocks x 256 thr (was 2048): each wave owns one n row and is fully
//    wave-autonomous in phase B (readlane broadcast, no red[] LDS, no 2nd
//    barrier).
//  - breakpoint o=0 plane (544 floats, identical for ALL n) staged once per
//    block into LDS: 544 uncoalesced L2 loads per block instead of 17 per
//    (n,i) thread (~70 MB -> ~17 MB of L2 traffic).
//  - float2 yp loads: lanes 0..31 read the seg row, lanes 32..63 the seg+1
//    row; halves combined by one shfl_xor(32) at the end. Halves the VMEM
//    instruction count and makes the final store a coalesced 256B float2
//    store per row.
#define PN   2048
#define PIN  32
#define PSEG 16
#define POUT 64
#define NPB  4                      // n rows per block (1 per wave)
#define NBP  (PIN * (PSEG + 1))     // 544 breakpoint-plane elements

__device__ __forceinline__ float bcast_f(float v, int k) {
    return __uint_as_float(__builtin_amdgcn_readlane(__float_as_uint(v), k));
}

__global__ __launch_bounds__(256) void seg_fused(
    const float* __restrict__ x_in,   // (N, IN)
    const float* __restrict__ xp,     // (IN, SEG+1, OUT)
    const float* __restrict__ yp,     // (IN, SEG+1, OUT)
    float* __restrict__ out)          // (N, OUT)
{
    __shared__ float bp[NBP];

    const int tid = threadIdx.x;

    // Cooperative stage of the o=0 breakpoint plane (shared by every n).
    bp[tid]       = xp[(size_t)tid * POUT];
    bp[tid + 256] = xp[(size_t)(tid + 256) * POUT];
    if (tid < NBP - 512) bp[tid + 512] = xp[(size_t)(tid + 512) * POUT];

    const int w    = tid >> 6;        // wave id -> n row
    const int lane = tid & 63;
    const int i    = lane & 31;       // lanes 32..63 duplicate 0..31 in phase A
    const int n    = blockIdx.x * NPB + w;
    const float x  = x_in[n * PIN + i];

    __syncthreads();                  // the only barrier

    // Phase A (per lane): segment search for (n, i).
    float b[PSEG + 1];
#pragma unroll
    for (int s = 0; s <= PSEG; ++s) b[s] = bp[i * (PSEG + 1) + s];
    int   seg = 0;
    float lo = b[0], hi = b[1];
#pragma unroll
    for (int s = 1; s < PSEG; ++s) {
        const bool c = (x >= b[s]);
        seg = c ? s : seg;
        lo  = c ? b[s] : lo;
        hi  = c ? b[s + 1] : hi;
    }
    float d = hi - lo;
    d = (d == 0.0f) ? 1e-4f : d;
    const float t    = (x - lo) / d;
    const float vlo  = 1.0f - t;                    // weight of yp[i,seg,:]
    const float vhi  = t;                           // weight of yp[i,seg+1,:]
    const int   base = (i * (PSEG + 1) + seg) * POUT;

    // Phase B: wave-local accumulation over i. half 0 reads the seg row,
    // half 1 the seg+1 row; each lane holds a float2 (o = 2*oo, 2*oo+1).
    const int half = lane >> 5;
    const int oo   = lane & 31;

    float2 acc = make_float2(0.0f, 0.0f);
#pragma unroll 8
    for (int k = 0; k < PIN; ++k) {
        const float wl = bcast_f(vlo, k);
        const float wh = bcast_f(vhi, k);
        const int   bk = __builtin_amdgcn_readlane(base, k);   // wave-uniform
        const float2 y = ((const float2*)(yp + bk + half * POUT))[oo];
        const float wk = half ? wh : wl;
        acc.x = fmaf(wk, y.x, acc.x);
        acc.y = fmaf(wk, y.y, acc.y);
    }
    acc.x += __shfl_xor(acc.x, 32);
    acc.y += __shfl_xor(acc.y, 32);

    if (half == 0)
        ((float2*)(out + (size_t)n * POUT))[oo] = acc;
}

extern "C" void kernel_launch(void* const* d_in, const int* in_sizes, int n_in,
                              void* d_out, int out_size, void* d_ws, size_t ws_size,
                              hipStream_t stream)
{
    const float* x_in = (const float*)d_in[0];
    const float* xp   = (const float*)d_in[1];
    const float* yp   = (const float*)d_in[2];
    float* out        = (float*)d_out;

    seg_fused<<<dim3(PN / NPB), dim3(256), 0, stream>>>(x_in, xp, yp, out);
}